// Round 13
// baseline (146.752 us; speedup 1.0000x reference)
//
#include <hip/hip_runtime.h>

#define WW 320           // input width/height
#define OWID 314         // output cols
#define OHEI 314         // output rows
#define BB 64            // batch
#define CPW 122          // output cols OWNED per wave (61 lanes x 2)
#define NCW 3            // col-waves (3*122 = 366 >= 314)
#define BROWS 20         // output rows per band
#define NBANDB 4         // bands per block
#define WPB (NCW * NBANDB)  // 12 waves per block (R11-proven co-residency)
#define NTH (WPB * 64)   // 768 threads
#define NBLK (BB * 4)    // 64 images x 4 row-quarters = 256 blocks = 1/CU

// One row's 4 coalesced float2 loads (2 cols/lane -> wave spans 128 cols).
#define LOADR(K_)                                                             \
  {                                                                           \
    const int rr  = min(r0 + g7 + (K_), WW - 1);  /* clamp; tail masked */    \
    const int off = rr * WW;                      /* wave-uniform */          \
    gx0[K_] = *(const float2*)(X0p + off);                                    \
    gx1[K_] = *(const float2*)(X1p + off);                                    \
    gy0[K_] = *(const float2*)(Y0p + off);                                    \
    gy1[K_] = *(const float2*)(Y1p + off);                                    \
  }

// Horizontal 7-tap for an even/odd column pair from per-lane pair moments:
// T = P(L)+P(L+1)+P(L+2) with P = VE+VO;  HE = cols 2L..2L+6 = T + VE(L+3);
// HO = cols 2L+1..2L+7 = T - VE(L) + P(L+3).  4 shfls serve BOTH outputs.
#define HPAIR(VE, VO, HE, HO)                                                 \
  {                                                                           \
    const float P  = (VE) + (VO);                                             \
    const float t1 = P + __shfl_down(P, 1, 64);                               \
    const float T  = t1 + __shfl_down(P, 2, 64);                              \
    HE = T + __shfl_down((VE), 3, 64);                                        \
    HO = T - (VE) + __shfl_down(P, 3, 64);                                    \
  }

// One input row step: vertical ring of 4 moments x {even,odd}, horizontal
// via HPAIR, SSIM for the lane's two columns. K_ literal, g7 % 7 == 0.
#define BODY(K_)                                                              \
  {                                                                           \
    const float2 x0 = gx0[K_], x1 = gx1[K_];                                  \
    const float2 y0 = gy0[K_], y1 = gy1[K_];                                  \
    const float pxe  = x0.x + x1.x,  pxo  = x0.y + x1.y;                      \
    const float pye  = y0.x + y1.x,  pyo  = y0.y + y1.y;                      \
    const float p2e  = x0.x * x0.x + x1.x * x1.x + y0.x * y0.x + y1.x * y1.x; \
    const float p2o  = x0.y * x0.y + x1.y * x1.y + y0.y * y0.y + y1.y * y1.y; \
    const float pxye = x0.x * y0.x + x1.x * y1.x;                             \
    const float pxyo = x0.y * y0.y + x1.y * y1.y;                             \
    V0e += pxe  - ring[K_][0]; ring[K_][0] = pxe;                             \
    V0o += pxo  - ring[K_][1]; ring[K_][1] = pxo;                             \
    V1e += pye  - ring[K_][2]; ring[K_][2] = pye;                             \
    V1o += pyo  - ring[K_][3]; ring[K_][3] = pyo;                             \
    V2e += p2e  - ring[K_][4]; ring[K_][4] = p2e;                             \
    V2o += p2o  - ring[K_][5]; ring[K_][5] = p2o;                             \
    V3e += pxye - ring[K_][6]; ring[K_][6] = pxye;                            \
    V3o += pxyo - ring[K_][7]; ring[K_][7] = pxyo;                            \
    const int i_ = g7 + (K_);                                                 \
    const int t  = r0 + i_ - 6;               /* output row */                \
    if (i_ >= 6 && t < tmax) {                /* wave-uniform mask */         \
      float H0e, H0o, H1e, H1o, H2e, H2o, H3e, H3o;                           \
      HPAIR(V0e, V0o, H0e, H0o)                                               \
      HPAIR(V1e, V1o, H1e, H1o)                                               \
      HPAIR(V2e, V2o, H2e, H2o)                                               \
      HPAIR(V3e, V3o, H3e, H3o)                                               \
      {                                                                       \
        const float ux = H0e * inv, uy = H1e * inv;                           \
        const float u2 = H2e * inv, uxy = H3e * inv;                          \
        const float vxy = cn * (uxy - ux * uy);                               \
        const float v2m = cn * (u2 - ux * ux - uy * uy);                      \
        const float A1 = 2.0f * ux * uy + C1;                                 \
        const float A2 = 2.0f * vxy + C2;                                     \
        const float B1 = ux * ux + uy * uy + C1;                              \
        const float B2 = v2m + C2;                                            \
        ssum += cmf0 * (A1 * A2) / (B1 * B2);                                 \
      }                                                                       \
      {                                                                       \
        const float ux = H0o * inv, uy = H1o * inv;                           \
        const float u2 = H2o * inv, uxy = H3o * inv;                          \
        const float vxy = cn * (uxy - ux * uy);                               \
        const float v2m = cn * (u2 - ux * ux - uy * uy);                      \
        const float A1 = 2.0f * ux * uy + C1;                                 \
        const float A2 = 2.0f * vxy + C2;                                     \
        const float B1 = ux * ux + uy * uy + C1;                              \
        const float B2 = v2m + C2;                                            \
        ssum += cmf1 * (A1 * A2) / (B1 * B2);                                 \
      }                                                                       \
    }                                                                         \
  }

// Transposed, 2 cols/lane (float2): 3 col-waves instead of 6 -> per-CU
// wave-load count halves (1344 vs 2352) and each 7-row group carries 2x
// compute to hide its stall under 3 waves/SIMD. R11 group structure kept
// verbatim (load-then-consume; no ping-pong — R12's spill lesson).
__global__ __launch_bounds__(NTH, 1) void ssim_main(
    const float* __restrict__ X, const float* __restrict__ Y,
    const float* __restrict__ dr, double* __restrict__ acc,
    unsigned* __restrict__ counter, float* __restrict__ out)
{
    const int w    = threadIdx.x >> 6;        // wave in block (0..11)
    const int lane = threadIdx.x & 63;
    const int b    = blockIdx.x >> 2;         // image
    const int q    = blockIdx.x & 3;          // row-quarter
    const int band = q * NBANDB + (w / NCW);  // 0..15
    const int r0   = band * BROWS;            // first output row of band
    const int tmax = min(r0 + BROWS, OHEI);   // band-exclusive output rows

    const int base = (w % NCW) * CPW;         // col-wave base
    int c0 = base + 2 * lane;                 // lane's even column
    const float cmf0 = (lane <= 60 && c0     < OWID) ? 1.0f : 0.0f;
    const float cmf1 = (lane <= 60 && c0 + 1 < OWID) ? 1.0f : 0.0f;
    if (c0 > WW - 2) c0 = WW - 2;             // clamp float2 in-bounds (even)

    const size_t plane = (size_t)WW * WW;
    const float* X0p = X + (size_t)b * 2 * plane + c0;
    const float* X1p = X0p + plane;
    const float* Y0p = Y + (size_t)b * 2 * plane + c0;
    const float* Y1p = Y0p + plane;

    const float d  = dr[b];
    const float C1 = (0.01f * d) * (0.01f * d);
    const float C2 = (0.03f * d) * (0.03f * d);
    const float inv = 1.0f / 49.0f;
    const float cn  = 49.0f / 48.0f;

    float ring[7][8];                         // 56 regs
    #pragma unroll
    for (int k = 0; k < 7; ++k)
        #pragma unroll
        for (int m = 0; m < 8; ++m) ring[k][m] = 0.0f;

    float V0e = 0.0f, V0o = 0.0f, V1e = 0.0f, V1o = 0.0f;
    float V2e = 0.0f, V2o = 0.0f, V3e = 0.0f, V3o = 0.0f;
    float ssum = 0.0f;
    float2 gx0[7], gx1[7], gy0[7], gy1[7];    // group buffer (56 regs)

    // 26 live input rows -> 4 groups of 7 (28 steps; 2 dead, tmax-masked).
    #pragma unroll 1
    for (int g7 = 0; g7 < 28; g7 += 7) {
        LOADR(0) LOADR(1) LOADR(2) LOADR(3) LOADR(4) LOADR(5) LOADR(6)
        BODY(0) BODY(1) BODY(2) BODY(3) BODY(4) BODY(5) BODY(6)
    }

    // ---- reduction: wave shuffle (double) -> LDS -> one atomic per block ----
    double local = (double)ssum;
    #pragma unroll
    for (int off = 32; off > 0; off >>= 1)
        local += __shfl_down(local, off, 64);
    __shared__ double wsum[WPB];
    if (lane == 0) wsum[w] = local;
    __syncthreads();
    if (threadIdx.x == 0) {
        double tot = 0.0;
        #pragma unroll
        for (int k = 0; k < WPB; ++k) tot += wsum[k];
        atomicAdd(acc, tot);
        __threadfence();
        unsigned ticket = atomicAdd(counter, 1u);
        if (ticket == NBLK - 1) {
            double stot = atomicAdd(acc, 0.0);   // device-scope coherent read
            const double N = (double)BB * (double)OHEI * (double)OWID;
            out[0] = (float)(1.0 - stot / N);
        }
    }
}

extern "C" void kernel_launch(void* const* d_in, const int* in_sizes, int n_in,
                              void* d_out, int out_size, void* d_ws, size_t ws_size,
                              hipStream_t stream)
{
    const float* X  = (const float*)d_in[0];
    const float* Y  = (const float*)d_in[1];
    const float* dr = (const float*)d_in[2];
    // d_in[3] is the box kernel w (all 1/49) — folded into constants.
    double*   acc     = (double*)d_ws;
    unsigned* counter = (unsigned*)((char*)d_ws + 8);
    float*    out     = (float*)d_out;

    hipMemsetAsync(d_ws, 0, 16, stream);
    ssim_main<<<dim3(NBLK), dim3(NTH), 0, stream>>>(X, Y, dr, acc, counter, out);
}